// Round 4
// baseline (820.090 us; speedup 1.0000x reference)
//
#include <hip/hip_runtime.h>
#include <math.h>

// ---------------------------------------------------------------------------
// Round 4: same 3xf16 split-precision MFMA scheme as R3 (verified correct,
// absmax 0.0078 vs 0.052 threshold), restructured for memory:
//  - octant XCD swizzle: block%8 = spatial octant -> each XCD's private L2
//    serves its own halo re-reads (R3: 3.1x HBM overfetch from y-halo split
//    across XCDs).
//  - 64-pos tiles (16x2x2), LDS 50.7KB -> 3 blocks/CU; halo 4.5x vs 9.56x.
//  - k2 stride-2 LDS reads de-conflicted via even/odd x interleave.
//  - conv_out dual-writes hx packed f16 (levels>=1) so gate skips f32 cvt.
// ---------------------------------------------------------------------------

typedef _Float16 f16;
typedef _Float16 f16x8 __attribute__((ext_vector_type(8)));
typedef _Float16 f16x4 __attribute__((ext_vector_type(4)));
typedef float    f32x4 __attribute__((ext_vector_type(4)));

#define PIX 88   // f16 per LDS pixel-half: 64 payload (32 hi | 32 lo) + 24 pad

// Pack weights into MFMA A-fragment order (same layout as R3).
__global__ void pack_w(const float* __restrict__ w, f16* __restrict__ wp,
                       int Cin, int taps, int CH, int NMT)
{
    const int lane = threadIdx.x;  // 0..63
    const int e   = blockIdx.x;
    const int gmt = e % NMT;
    const int sel = (e / NMT) % 2;
    const int h   = (e / (NMT * 2)) % CH;
    const int tap = e / (NMT * 2 * CH);
    const int cout = gmt * 16 + (lane & 15);
    const int cin0 = h * 32 + ((lane >> 4) & 3) * 8;
    f16x8 v;
    for (int j = 0; j < 8; ++j) {
        float x = w[((size_t)cout * Cin + cin0 + j) * taps + tap];
        f16 hi = (f16)x;
        v[j] = sel ? (f16)(x - (float)hi) : hi;
    }
    *(f16x8*)&wp[((size_t)e * 64 + lane) * 8] = v;
}

// Octant swizzle: bid -> (xc,yb,zb). If all dims even and grid big, bid&7
// selects an octant so each XCD (round-robin) owns a compact subvolume.
template<int NXC, int NYC, int NZC>
__device__ inline void tile_coords(int bid, int& xc, int& yb, int& zb)
{
    if ((NXC % 2 == 0) && (NYC % 2 == 0) && (NZC % 2 == 0) && (NXC*NYC*NZC >= 64)) {
        const int o = bid & 7, j = bid >> 3;
        constexpr int HX = NXC / 2, HY = NYC / 2;
        xc = (j % HX) + (o & 1) * HX;
        yb = ((j / HX) % HY) + ((o >> 1) & 1) * HY;
        zb = (j / (HX * HY)) + (o >> 2) * (NZC / 2);
    } else {
        xc = bid % NXC;
        yb = (bid / NXC) % NYC;
        zb = bid / (NXC * NYC);
    }
}

// ---------------- k3 s1 SAME conv, Cin=64 (CH=2) ----------------
// Tile TX x TY x TZ = 64 out positions, 4 waves, each wave one 16-px n-tile
// and ALL NMT m-tiles. f16-act source is always C=64 layout [px][128].
template<int S, int TX, int TY, int TZ, int NMT, int ACT_C, bool SRCF32>
__global__ __launch_bounds__(256) void conv_k3(
    const void* __restrict__ in_, const f16* __restrict__ wp,
    const f16* __restrict__ addsrc, f16* __restrict__ act_out,
    float* __restrict__ f32_out, int relu, float scale)
{
    constexpr int S2 = S * S, S3 = S2 * S;
    constexpr int XP = TX + 2, YP = TY + 2, ZP = TZ + 2;
    constexpr int NPX = XP * YP * ZP;
    constexpr int NXC = S / TX, NYC = S / TY, NZC = S / TZ;
    constexpr int CH = 2;
    __shared__ __align__(16) f16 sm[NPX * PIX];

    int xc, yb, zb;
    tile_coords<NXC, NYC, NZC>(blockIdx.x, xc, yb, zb);
    const int x0 = xc * TX, y0 = yb * TY, z0 = zb * TZ;

    const int tid  = threadIdx.x;
    const int lane = tid & 63;
    const int wave = tid >> 6;
    const int i15  = lane & 15, quad = (lane >> 4) & 3;
    const int p = wave * 16 + i15;
    const int lx = p % TX, ly = (p / TX) % TY, lz = p / (TX * TY);

    f32x4 acc[NMT];
#pragma unroll
    for (int m = 0; m < NMT; ++m) { f32x4 z = {0.f, 0.f, 0.f, 0.f}; acc[m] = z; }

    for (int h = 0; h < CH; ++h) {
        __syncthreads();
        if (SRCF32) {
            const float* src = (const float*)in_;
            for (int it = tid; it < NPX * 8; it += 256) {
                const int xp = it % XP;
                const int rem = it / XP;
                const int row = rem % (YP * ZP);
                const int cc = rem / (YP * ZP);
                const int zr = row / YP, yr = row % YP;
                const int pz = z0 + zr - 1, py = y0 + yr - 1, px = x0 + xp - 1;
                const bool ok = (unsigned)pz < (unsigned)S && (unsigned)py < (unsigned)S
                             && (unsigned)px < (unsigned)S;
                f16x8 v;
                if (ok) {
                    const size_t pos = (size_t)(pz * S2 + py * S + px);
                    const int cbase = h * 32 + (cc & 3) * 8;
#pragma unroll
                    for (int j = 0; j < 8; ++j) {
                        float x = src[(size_t)(cbase + j) * S3 + pos];
                        f16 hi = (f16)x;
                        v[j] = (cc < 4) ? hi : (f16)(x - (float)hi);
                    }
                } else {
#pragma unroll
                    for (int j = 0; j < 8; ++j) v[j] = (f16)0.f;
                }
                sm[(row * XP + xp) * PIX + (cc & 3) * 8 + (cc >> 2) * 32] = v[0]; // placeholder avoid
                *(f16x8*)&sm[(row * XP + xp) * PIX + (cc & 3) * 8 + (cc >> 2) * 32] = v;
            }
        } else {
            const f16* src = (const f16*)in_;
            for (int it = tid; it < NPX * 8; it += 256) {
                const int cc = it & 7;
                const int pxl = it >> 3;
                const int xp = pxl % XP;
                const int row = pxl / XP;
                const int zr = row / YP, yr = row % YP;
                const int pz = z0 + zr - 1, py = y0 + yr - 1, px = x0 + xp - 1;
                const bool ok = (unsigned)pz < (unsigned)S && (unsigned)py < (unsigned)S
                             && (unsigned)px < (unsigned)S;
                f16x8 v;
                if (ok) {
                    const size_t pos = (size_t)(pz * S2 + py * S + px);
                    v = *(const f16x8*)&src[pos * 128 + (cc >> 2) * 64 + h * 32 + (cc & 3) * 8];
                } else {
#pragma unroll
                    for (int j = 0; j < 8; ++j) v[j] = (f16)0.f;
                }
                *(f16x8*)&sm[(row * XP + xp) * PIX + (cc & 3) * 8 + (cc >> 2) * 32] = v;
            }
        }
        __syncthreads();

        for (int dz = 0; dz < 3; ++dz) {
#pragma unroll
            for (int dy = 0; dy < 3; ++dy) {
#pragma unroll
                for (int dx = 0; dx < 3; ++dx) {
                    const int tap = dz * 9 + dy * 3 + dx;
                    const int pix = ((lz + dz) * YP + ly + dy) * XP + lx + dx;
                    const f16x8 bh = *(const f16x8*)&sm[pix * PIX + quad * 8];
                    const f16x8 bl = *(const f16x8*)&sm[pix * PIX + 32 + quad * 8];
#pragma unroll
                    for (int m = 0; m < NMT; ++m) {
                        const size_t eh = ((size_t)((tap * CH + h) * 2 + 0) * NMT + m) * 512 + lane * 8;
                        const size_t el = ((size_t)((tap * CH + h) * 2 + 1) * NMT + m) * 512 + lane * 8;
                        const f16x8 awh = *(const f16x8*)&wp[eh];
                        const f16x8 awl = *(const f16x8*)&wp[el];
                        acc[m] = __builtin_amdgcn_mfma_f32_16x16x32_f16(awh, bh, acc[m], 0, 0, 0);
                        acc[m] = __builtin_amdgcn_mfma_f32_16x16x32_f16(awh, bl, acc[m], 0, 0, 0);
                        acc[m] = __builtin_amdgcn_mfma_f32_16x16x32_f16(awl, bh, acc[m], 0, 0, 0);
                    }
                }
            }
        }
    }

    // epilogue: C/D layout col(=pos)=lane&15, row(=cout_local)=quad*4+r
    const int pg = (z0 + lz) * S2 + (y0 + ly) * S + x0 + lx;
#pragma unroll
    for (int m = 0; m < NMT; ++m) {
        float a[4];
#pragma unroll
        for (int r = 0; r < 4; ++r) a[r] = acc[m][r];
        if (addsrc) {
            const f16x4 ah = *(const f16x4*)&addsrc[(size_t)pg * 128 + m * 16 + quad * 4];
            const f16x4 al = *(const f16x4*)&addsrc[(size_t)pg * 128 + 64 + m * 16 + quad * 4];
#pragma unroll
            for (int r = 0; r < 4; ++r) a[r] += (float)ah[r] + (float)al[r];
        }
        if (relu) {
#pragma unroll
            for (int r = 0; r < 4; ++r) a[r] = fmaxf(a[r], 0.f);
        }
        if (act_out) {
            f16x4 hi, lo;
#pragma unroll
            for (int r = 0; r < 4; ++r) {
                hi[r] = (f16)a[r];
                lo[r] = (f16)(a[r] - (float)hi[r]);
            }
            *(f16x4*)&act_out[(size_t)pg * (2 * ACT_C) + m * 16 + quad * 4] = hi;
            *(f16x4*)&act_out[(size_t)pg * (2 * ACT_C) + ACT_C + m * 16 + quad * 4] = lo;
        }
        if (f32_out) {
#pragma unroll
            for (int r = 0; r < 4; ++r)
                f32_out[(size_t)(m * 16 + quad * 4 + r) * S3 + pg] = a[r] * scale;
        }
    }
}

// ---------------- k2 s2 VALID conv ----------------
// Tile TX x TY x TZ out (32 positions), 2 n-tiles x 2 m-groups over 4 waves.
// Input staged WITHOUT halo; x stored even/odd-interleaved (slot = x/2 +
// (x&1)*TX) so stride-2 reads are lane-consecutive (conflict-free).
template<int So, int TX, int TY, int TZ, int NMT, int CH, bool SRCF32, int SRC_C, bool GATE>
__global__ __launch_bounds__(256) void conv_k2(
    const void* __restrict__ in_, const f16* __restrict__ wp,
    f16* __restrict__ act_out, f16* __restrict__ cx, float src_scale)
{
    constexpr int So2 = So * So, So3 = So2 * So;
    constexpr int Si = 2 * So, Si2 = Si * Si, Si3 = Si2 * Si;
    constexpr int XI = 2 * TX, YI = 2 * TY, ZI = 2 * TZ;
    constexpr int NPX = XI * YI * ZI;
    constexpr int NXC = So / TX, NYC = So / TY, NZC = So / TZ;
    constexpr int MTW = NMT / 2;
    __shared__ __align__(16) f16 sm[NPX * PIX];

    int xc, yb, zb;
    tile_coords<NXC, NYC, NZC>(blockIdx.x, xc, yb, zb);
    const int x0 = xc * TX, y0 = yb * TY, z0 = zb * TZ;

    const int tid  = threadIdx.x;
    const int lane = tid & 63;
    const int wave = tid >> 6;
    const int i15  = lane & 15, quad = (lane >> 4) & 3;
    const int nt = wave & 1, mh = wave >> 1;
    const int p = nt * 16 + i15;
    const int lx = p % TX, ly = (p / TX) % TY, lz = p / (TX * TY);

    f32x4 acc[MTW];
#pragma unroll
    for (int m = 0; m < MTW; ++m) { f32x4 z = {0.f, 0.f, 0.f, 0.f}; acc[m] = z; }

    for (int h = 0; h < CH; ++h) {
        __syncthreads();
        if (SRCF32) {
            const float* src = (const float*)in_;
            for (int it = tid; it < NPX * 8; it += 256) {
                const int xp = it % XI;
                const int rem = it / XI;
                const int row = rem % (YI * ZI);
                const int cc = rem / (YI * ZI);
                const int zr = row / YI, yr = row % YI;
                const size_t pos = (size_t)((z0 * 2 + zr) * Si2 + (y0 * 2 + yr) * Si + x0 * 2 + xp);
                const int cbase = h * 32 + (cc & 3) * 8;
                f16x8 v;
#pragma unroll
                for (int j = 0; j < 8; ++j) {
                    float x = src[(size_t)(cbase + j) * Si3 + pos] * src_scale;
                    f16 hi = (f16)x;
                    v[j] = (cc < 4) ? hi : (f16)(x - (float)hi);
                }
                const int slot = (xp >> 1) + (xp & 1) * TX;
                *(f16x8*)&sm[(row * XI + slot) * PIX + (cc & 3) * 8 + (cc >> 2) * 32] = v;
            }
        } else {
            const f16* src = (const f16*)in_;
            for (int it = tid; it < NPX * 8; it += 256) {
                const int cc = it & 7;
                const int pxl = it >> 3;
                const int xp = pxl % XI;
                const int row = pxl / XI;
                const int zr = row / YI, yr = row % YI;
                const size_t pos = (size_t)((z0 * 2 + zr) * Si2 + (y0 * 2 + yr) * Si + x0 * 2 + xp);
                f16x8 v = *(const f16x8*)&src[pos * (2 * SRC_C) + (cc >> 2) * SRC_C + h * 32 + (cc & 3) * 8];
                const int slot = (xp >> 1) + (xp & 1) * TX;
                *(f16x8*)&sm[(row * XI + slot) * PIX + (cc & 3) * 8 + (cc >> 2) * 32] = v;
            }
        }
        __syncthreads();

#pragma unroll
        for (int dz = 0; dz < 2; ++dz) {
#pragma unroll
            for (int dy = 0; dy < 2; ++dy) {
#pragma unroll
                for (int dx = 0; dx < 2; ++dx) {
                    const int tap = dz * 4 + dy * 2 + dx;
                    const int pix = ((2 * lz + dz) * YI + 2 * ly + dy) * XI + lx + dx * TX;
                    const f16x8 bh = *(const f16x8*)&sm[pix * PIX + quad * 8];
                    const f16x8 bl = *(const f16x8*)&sm[pix * PIX + 32 + quad * 8];
#pragma unroll
                    for (int m = 0; m < MTW; ++m) {
                        const int gmt = mh * MTW + m;
                        const size_t eh = ((size_t)((tap * CH + h) * 2 + 0) * NMT + gmt) * 512 + lane * 8;
                        const size_t el = ((size_t)((tap * CH + h) * 2 + 1) * NMT + gmt) * 512 + lane * 8;
                        const f16x8 awh = *(const f16x8*)&wp[eh];
                        const f16x8 awl = *(const f16x8*)&wp[el];
                        acc[m] = __builtin_amdgcn_mfma_f32_16x16x32_f16(awh, bh, acc[m], 0, 0, 0);
                        acc[m] = __builtin_amdgcn_mfma_f32_16x16x32_f16(awh, bl, acc[m], 0, 0, 0);
                        acc[m] = __builtin_amdgcn_mfma_f32_16x16x32_f16(awl, bh, acc[m], 0, 0, 0);
                    }
                }
            }
        }
    }

    const int pg = (z0 + lz) * So2 + (y0 + ly) * So + x0 + lx;
#pragma unroll
    for (int m = 0; m < MTW; ++m) {
        const int gmt = mh * MTW + m;
        if (GATE) {
            f16x4 chi = *(const f16x4*)&cx[(size_t)pg * 128 + gmt * 16 + quad * 4];
            f16x4 clo = *(const f16x4*)&cx[(size_t)pg * 128 + 64 + gmt * 16 + quad * 4];
            f16x4 nhi, nlo;
#pragma unroll
            for (int r = 0; r < 4; ++r) {
                const float g = 1.0f / (1.0f + expf(-fmaxf(acc[m][r], 0.f)));
                float v = ((float)chi[r] + (float)clo[r]) * g;
                f16 hi = (f16)v;
                nhi[r] = hi;
                nlo[r] = (f16)(v - (float)hi);
            }
            *(f16x4*)&cx[(size_t)pg * 128 + gmt * 16 + quad * 4] = nhi;
            *(f16x4*)&cx[(size_t)pg * 128 + 64 + gmt * 16 + quad * 4] = nlo;
        } else {
            f16x4 hi, lo;
#pragma unroll
            for (int r = 0; r < 4; ++r) {
                const float a = fmaxf(acc[m][r], 0.f);   // ConvBlock relu
                hi[r] = (f16)a;
                lo[r] = (f16)(a - (float)hi[r]);
            }
            *(f16x4*)&act_out[(size_t)pg * 128 + gmt * 16 + quad * 4] = hi;
            *(f16x4*)&act_out[(size_t)pg * 128 + 64 + gmt * 16 + quad * 4] = lo;
        }
    }
}

extern "C" void kernel_launch(void* const* d_in, const int* in_sizes, int n_in,
                              void* d_out, int out_size, void* d_ws, size_t ws_size,
                              hipStream_t stream)
{
    const float* x     = (const float*)d_in[0];
    const float* w_h   = (const float*)d_in[1];
    const float* w_c0  = (const float*)d_in[2];
    const float* w_r0  = (const float*)d_in[3];
    const float* w_r1  = (const float*)d_in[4];
    const float* w_c1  = (const float*)d_in[5];
    const float* w_out = (const float*)d_in[6];
    float* out = (float*)d_out;
    f16* ws = (f16*)d_ws;

    // ws layout (f16 units)
    size_t o = 0;
    f16* wp_h   = ws + o; o += (size_t)8 * 1 * 2 * 4 * 512;
    f16* wp_c0  = ws + o; o += (size_t)8 * 2 * 2 * 4 * 512;
    f16* wp_r0  = ws + o; o += (size_t)27 * 2 * 2 * 4 * 512;
    f16* wp_r1  = ws + o; o += (size_t)27 * 2 * 2 * 4 * 512;
    f16* wp_c1  = ws + o; o += (size_t)27 * 2 * 2 * 4 * 512;
    f16* wp_out = ws + o; o += (size_t)27 * 2 * 2 * 2 * 512;
    const size_t ABUF = (size_t)32 * 32 * 32 * 128;            // C=64 act, 32^3
    f16* y_buf  = ws + o; o += ABUF;
    f16* t_buf  = ws + o; o += ABUF;
    f16* cx     = ws + o; o += ABUF;
    f16* hx_act = ws + o; o += (size_t)32 * 32 * 32 * 64;      // C=32 act, 32^3

    size_t offs[4];
    offs[0] = 0;
    offs[1] = offs[0] + (size_t)32 * 64 * 64 * 64;
    offs[2] = offs[1] + (size_t)32 * 32 * 32 * 32;
    offs[3] = offs[2] + (size_t)32 * 16 * 16 * 16;

    const dim3 blk(256);

    pack_w<<<dim3(8  * 1 * 2 * 4), dim3(64), 0, stream>>>(w_h,   wp_h,   32, 8,  1, 4);
    pack_w<<<dim3(8  * 2 * 2 * 4), dim3(64), 0, stream>>>(w_c0,  wp_c0,  64, 8,  2, 4);
    pack_w<<<dim3(27 * 2 * 2 * 4), dim3(64), 0, stream>>>(w_r0,  wp_r0,  64, 27, 2, 4);
    pack_w<<<dim3(27 * 2 * 2 * 4), dim3(64), 0, stream>>>(w_r1,  wp_r1,  64, 27, 2, 4);
    pack_w<<<dim3(27 * 2 * 2 * 4), dim3(64), 0, stream>>>(w_c1,  wp_c1,  64, 27, 2, 4);
    pack_w<<<dim3(27 * 2 * 2 * 2), dim3(64), 0, stream>>>(w_out, wp_out, 64, 27, 2, 2);

    // hx0 = 0.5 * conv_out(x) @64^3. Tile 16x2x2 -> grid 4*32*32.
    conv_k3<64, 16, 2, 2, 2, 32, true><<<dim3(4096), blk, 0, stream>>>(
        x, wp_out, nullptr, nullptr, out + offs[0], 0, 0.5f);

    // ---- level 0: 64 -> 32 ----
    conv_k2<32, 16, 2, 1, 4, 2, true, 64, false><<<dim3(1024), blk, 0, stream>>>(
        x, wp_c0, y_buf, nullptr, 1.0f);
    conv_k3<32, 16, 2, 2, 4, 64, false><<<dim3(512), blk, 0, stream>>>(
        y_buf, wp_r0, nullptr, t_buf, nullptr, 1, 1.0f);
    conv_k3<32, 16, 2, 2, 4, 64, false><<<dim3(512), blk, 0, stream>>>(
        t_buf, wp_r1, y_buf, y_buf, nullptr, 0, 1.0f);
    conv_k3<32, 16, 2, 2, 4, 64, false><<<dim3(512), blk, 0, stream>>>(
        y_buf, wp_c1, nullptr, cx, nullptr, 0, 1.0f);
    // gate L0 reads hx from d_out f32 (0.5-scaled; undo with src_scale=2)
    conv_k2<32, 16, 2, 1, 4, 1, true, 32, true><<<dim3(1024), blk, 0, stream>>>(
        out + offs[0], wp_h, nullptr, cx, 2.0f);
    // hx1: write f32*0.5 to d_out AND unscaled packed f16 for next gate
    conv_k3<32, 16, 2, 2, 2, 32, false><<<dim3(512), blk, 0, stream>>>(
        cx, wp_out, nullptr, hx_act, out + offs[1], 0, 0.5f);

    // ---- level 1: 32 -> 16 ----
    conv_k2<16, 16, 2, 1, 4, 2, false, 64, false><<<dim3(128), blk, 0, stream>>>(
        cx, wp_c0, y_buf, nullptr, 1.0f);
    conv_k3<16, 16, 2, 2, 4, 64, false><<<dim3(64), blk, 0, stream>>>(
        y_buf, wp_r0, nullptr, t_buf, nullptr, 1, 1.0f);
    conv_k3<16, 16, 2, 2, 4, 64, false><<<dim3(64), blk, 0, stream>>>(
        t_buf, wp_r1, y_buf, y_buf, nullptr, 0, 1.0f);
    conv_k3<16, 16, 2, 2, 4, 64, false><<<dim3(64), blk, 0, stream>>>(
        y_buf, wp_c1, nullptr, cx, nullptr, 0, 1.0f);
    conv_k2<16, 16, 2, 1, 4, 1, false, 32, true><<<dim3(128), blk, 0, stream>>>(
        hx_act, wp_h, nullptr, cx, 1.0f);
    conv_k3<16, 16, 2, 2, 2, 32, false><<<dim3(64), blk, 0, stream>>>(
        cx, wp_out, nullptr, hx_act, out + offs[2], 0, 0.5f);

    // ---- level 2: 16 -> 8 ----
    conv_k2<8, 8, 4, 1, 4, 2, false, 64, false><<<dim3(16), blk, 0, stream>>>(
        cx, wp_c0, y_buf, nullptr, 1.0f);
    conv_k3<8, 8, 4, 2, 4, 64, false><<<dim3(8), blk, 0, stream>>>(
        y_buf, wp_r0, nullptr, t_buf, nullptr, 1, 1.0f);
    conv_k3<8, 8, 4, 2, 4, 64, false><<<dim3(8), blk, 0, stream>>>(
        t_buf, wp_r1, y_buf, y_buf, nullptr, 0, 1.0f);
    conv_k3<8, 8, 4, 2, 4, 64, false><<<dim3(8), blk, 0, stream>>>(
        y_buf, wp_c1, nullptr, cx, nullptr, 0, 1.0f);
    conv_k2<8, 8, 4, 1, 4, 1, false, 32, true><<<dim3(16), blk, 0, stream>>>(
        hx_act, wp_h, nullptr, cx, 1.0f);
    conv_k3<8, 8, 4, 2, 2, 32, false><<<dim3(8), blk, 0, stream>>>(
        cx, wp_out, nullptr, nullptr, out + offs[3], 0, 0.5f);
}

// Round 5
// 563.852 us; speedup vs baseline: 1.4544x; 1.4544x over previous
//
#include <hip/hip_runtime.h>
#include <math.h>

// ---------------------------------------------------------------------------
// Round 5: same 3xf16 split-precision MFMA numerics (verified, absmax 0.0078
// vs 0.052 threshold). Changes vs R4 (which was weight-L2-refetch bound:
// MfmaUtil 17%, HBM 6%, weight fragments re-read 1KB/wave/tap ~3.5GB):
//  - m-split waves (2 ngroup x 2 mgroup): halves per-block weight traffic.
//  - NT n-tiles per wave on big kernels: one A-fragment -> NT MFMA triplets.
//  - PIX 88 -> 72 (16B aligned, bank stride 4 mod 32: 2-way = free) ->
//    smaller LDS, 3 blocks/CU at S=32.
//  - small levels back to 32-px tiles (L1 grid 128, L2 grid 16).
//  - single merged weight-pack launch.
// ---------------------------------------------------------------------------

typedef _Float16 f16;
typedef _Float16 f16x8 __attribute__((ext_vector_type(8)));
typedef _Float16 f16x4 __attribute__((ext_vector_type(4)));
typedef float    f32x4 __attribute__((ext_vector_type(4)));

#define PIX 72   // f16 per LDS pixel: 64 payload (32 hi | 32 lo) + 8 pad

// ---- weight packing (all 6 weights in one launch) ----
__device__ inline void pack_one(const float* __restrict__ w, f16* __restrict__ wp,
                                int Cin, int taps, int CH, int NMT, int e, int lane)
{
    const int gmt = e % NMT;
    const int sel = (e / NMT) % 2;
    const int h   = (e / (NMT * 2)) % CH;
    const int tap = e / (NMT * 2 * CH);
    const int cout = gmt * 16 + (lane & 15);
    const int cin0 = h * 32 + ((lane >> 4) & 3) * 8;
    f16x8 v;
    for (int j = 0; j < 8; ++j) {
        float x = w[((size_t)cout * Cin + cin0 + j) * taps + tap];
        f16 hi = (f16)x;
        v[j] = sel ? (f16)(x - (float)hi) : hi;
    }
    *(f16x8*)&wp[((size_t)e * 64 + lane) * 8] = v;
}

__global__ void pack_all(
    const float* wh, const float* wc0, const float* wr0,
    const float* wr1, const float* wc1, const float* wout,
    f16* ph, f16* pc0, f16* pr0, f16* pr1, f16* pc1, f16* pout)
{
    const int b = blockIdx.x, lane = threadIdx.x;
    if      (b < 64)   pack_one(wh,   ph,   32, 8,  1, 4, b,        lane);
    else if (b < 192)  pack_one(wc0,  pc0,  64, 8,  2, 4, b - 64,   lane);
    else if (b < 624)  pack_one(wr0,  pr0,  64, 27, 2, 4, b - 192,  lane);
    else if (b < 1056) pack_one(wr1,  pr1,  64, 27, 2, 4, b - 624,  lane);
    else if (b < 1488) pack_one(wc1,  pc1,  64, 27, 2, 4, b - 1056, lane);
    else               pack_one(wout, pout, 64, 27, 2, 2, b - 1488, lane);
}

// Octant swizzle for XCD L2 locality.
template<int NXC, int NYC, int NZC>
__device__ inline void tile_coords(int bid, int& xc, int& yb, int& zb)
{
    if ((NXC % 2 == 0) && (NYC % 2 == 0) && (NZC % 2 == 0) && (NXC*NYC*NZC >= 64)) {
        const int o = bid & 7, j = bid >> 3;
        constexpr int HX = NXC / 2, HY = NYC / 2;
        xc = (j % HX) + (o & 1) * HX;
        yb = ((j / HX) % HY) + ((o >> 1) & 1) * HY;
        zb = (j / (HX * HY)) + (o >> 2) * (NZC / 2);
    } else {
        xc = bid % NXC;
        yb = (bid / NXC) % NYC;
        zb = bid / (NXC * NYC);
    }
}

// ---------------- k3 s1 SAME conv, Cin=64 ----------------
// 4 waves = 2 n-groups x 2 m-groups. Each wave: NT n-tiles (16 px each),
// MTW = NMT/2 m-tiles. Block px = 2*NT*16 = TX*TY*TZ.
template<int S, int TX, int TY, int TZ, int NT, int NMT, int ACT_C, bool SRCF32>
__global__ __launch_bounds__(256) void conv_k3(
    const void* __restrict__ in_, const f16* __restrict__ wp,
    const f16* __restrict__ addsrc, f16* __restrict__ act_out,
    float* __restrict__ f32_out, int relu, float scale)
{
    constexpr int S2 = S * S, S3 = S2 * S;
    constexpr int XP = TX + 2, YP = TY + 2, ZP = TZ + 2;
    constexpr int NPX = XP * YP * ZP;
    constexpr int NXC = S / TX, NYC = S / TY, NZC = S / TZ;
    constexpr int CH = 2;
    constexpr int MTW = NMT / 2;
    static_assert(TX * TY * TZ == 2 * NT * 16, "tile/wave mismatch");
    __shared__ __align__(16) f16 sm[NPX * PIX];

    int xc, yb, zb;
    tile_coords<NXC, NYC, NZC>(blockIdx.x, xc, yb, zb);
    const int x0 = xc * TX, y0 = yb * TY, z0 = zb * TZ;

    const int tid  = threadIdx.x;
    const int lane = tid & 63;
    const int wave = tid >> 6;
    const int i15  = lane & 15, quad = (lane >> 4) & 3;
    const int ng = wave & 1, mh = wave >> 1;

    int lx[NT], ly[NT], lz[NT];
#pragma unroll
    for (int t = 0; t < NT; ++t) {
        const int p = (ng * NT + t) * 16 + i15;
        lx[t] = p % TX; ly[t] = (p / TX) % TY; lz[t] = p / (TX * TY);
    }

    f32x4 acc[NT][MTW];
#pragma unroll
    for (int t = 0; t < NT; ++t)
#pragma unroll
        for (int m = 0; m < MTW; ++m) { f32x4 z = {0.f,0.f,0.f,0.f}; acc[t][m] = z; }

    for (int h = 0; h < CH; ++h) {
        __syncthreads();
        if (SRCF32) {
            const float* src = (const float*)in_;
            for (int it = tid; it < NPX * 8; it += 256) {
                const int xp = it % XP;
                const int rem = it / XP;
                const int row = rem % (YP * ZP);
                const int cc = rem / (YP * ZP);
                const int zr = row / YP, yr = row % YP;
                const int pz = z0 + zr - 1, py = y0 + yr - 1, px = x0 + xp - 1;
                const bool ok = (unsigned)pz < (unsigned)S && (unsigned)py < (unsigned)S
                             && (unsigned)px < (unsigned)S;
                f16x8 v;
                if (ok) {
                    const size_t pos = (size_t)(pz * S2 + py * S + px);
                    const int cbase = h * 32 + (cc & 3) * 8;
#pragma unroll
                    for (int j = 0; j < 8; ++j) {
                        float x = src[(size_t)(cbase + j) * S3 + pos];
                        f16 hi = (f16)x;
                        v[j] = (cc < 4) ? hi : (f16)(x - (float)hi);
                    }
                } else {
#pragma unroll
                    for (int j = 0; j < 8; ++j) v[j] = (f16)0.f;
                }
                *(f16x8*)&sm[(row * XP + xp) * PIX + (cc & 3) * 8 + (cc >> 2) * 32] = v;
            }
        } else {
            const f16* src = (const f16*)in_;
            for (int it = tid; it < NPX * 8; it += 256) {
                const int cc = it & 7;
                const int pxl = it >> 3;
                const int xp = pxl % XP;
                const int row = pxl / XP;
                const int zr = row / YP, yr = row % YP;
                const int pz = z0 + zr - 1, py = y0 + yr - 1, px = x0 + xp - 1;
                const bool ok = (unsigned)pz < (unsigned)S && (unsigned)py < (unsigned)S
                             && (unsigned)px < (unsigned)S;
                f16x8 v;
                if (ok) {
                    const size_t pos = (size_t)(pz * S2 + py * S + px);
                    v = *(const f16x8*)&src[pos * 128 + (cc >> 2) * 64 + h * 32 + (cc & 3) * 8];
                } else {
#pragma unroll
                    for (int j = 0; j < 8; ++j) v[j] = (f16)0.f;
                }
                *(f16x8*)&sm[(row * XP + xp) * PIX + (cc & 3) * 8 + (cc >> 2) * 32] = v;
            }
        }
        __syncthreads();

        for (int dz = 0; dz < 3; ++dz) {
#pragma unroll
            for (int dy = 0; dy < 3; ++dy) {
#pragma unroll
                for (int dx = 0; dx < 3; ++dx) {
                    const int tap = dz * 9 + dy * 3 + dx;
                    f16x8 awh[MTW], awl[MTW];
#pragma unroll
                    for (int m = 0; m < MTW; ++m) {
                        const int gm = mh * MTW + m;
                        awh[m] = *(const f16x8*)&wp[((size_t)((tap * CH + h) * 2 + 0) * NMT + gm) * 512 + lane * 8];
                        awl[m] = *(const f16x8*)&wp[((size_t)((tap * CH + h) * 2 + 1) * NMT + gm) * 512 + lane * 8];
                    }
#pragma unroll
                    for (int t = 0; t < NT; ++t) {
                        const int pix = ((lz[t] + dz) * YP + ly[t] + dy) * XP + lx[t] + dx;
                        const f16x8 bh = *(const f16x8*)&sm[pix * PIX + quad * 8];
                        const f16x8 bl = *(const f16x8*)&sm[pix * PIX + 32 + quad * 8];
#pragma unroll
                        for (int m = 0; m < MTW; ++m) {
                            acc[t][m] = __builtin_amdgcn_mfma_f32_16x16x32_f16(awh[m], bh, acc[t][m], 0, 0, 0);
                            acc[t][m] = __builtin_amdgcn_mfma_f32_16x16x32_f16(awh[m], bl, acc[t][m], 0, 0, 0);
                            acc[t][m] = __builtin_amdgcn_mfma_f32_16x16x32_f16(awl[m], bh, acc[t][m], 0, 0, 0);
                        }
                    }
                }
            }
        }
    }

    // epilogue: C/D layout col(=pos)=lane&15, row(=cout_local)=quad*4+r
#pragma unroll
    for (int t = 0; t < NT; ++t) {
        const int pg = (z0 + lz[t]) * S2 + (y0 + ly[t]) * S + x0 + lx[t];
#pragma unroll
        for (int m = 0; m < MTW; ++m) {
            const int gm = mh * MTW + m;
            float a[4];
#pragma unroll
            for (int r = 0; r < 4; ++r) a[r] = acc[t][m][r];
            if (addsrc) {
                const f16x4 ah = *(const f16x4*)&addsrc[(size_t)pg * 128 + gm * 16 + quad * 4];
                const f16x4 al = *(const f16x4*)&addsrc[(size_t)pg * 128 + 64 + gm * 16 + quad * 4];
#pragma unroll
                for (int r = 0; r < 4; ++r) a[r] += (float)ah[r] + (float)al[r];
            }
            if (relu) {
#pragma unroll
                for (int r = 0; r < 4; ++r) a[r] = fmaxf(a[r], 0.f);
            }
            if (act_out) {
                f16x4 hi, lo;
#pragma unroll
                for (int r = 0; r < 4; ++r) {
                    hi[r] = (f16)a[r];
                    lo[r] = (f16)(a[r] - (float)hi[r]);
                }
                *(f16x4*)&act_out[(size_t)pg * (2 * ACT_C) + gm * 16 + quad * 4] = hi;
                *(f16x4*)&act_out[(size_t)pg * (2 * ACT_C) + ACT_C + gm * 16 + quad * 4] = lo;
            }
            if (f32_out) {
#pragma unroll
                for (int r = 0; r < 4; ++r)
                    f32_out[(size_t)(gm * 16 + quad * 4 + r) * S3 + pg] = a[r] * scale;
            }
        }
    }
}

// ---------------- k2 s2 VALID conv ----------------
// 32 out px per block (2 ngroups x 16), m-split. Even/odd x-interleaved LDS
// slots keep stride-2 reads conflict-free.
template<int So, int TX, int TY, int TZ, int NMT, int CH, bool SRCF32, int SRC_C, bool GATE>
__global__ __launch_bounds__(256) void conv_k2(
    const void* __restrict__ in_, const f16* __restrict__ wp,
    f16* __restrict__ act_out, f16* __restrict__ cx, float src_scale)
{
    constexpr int So2 = So * So;
    constexpr int Si = 2 * So, Si2 = Si * Si, Si3 = Si2 * Si;
    constexpr int XI = 2 * TX, YI = 2 * TY, ZI = 2 * TZ;
    constexpr int NPX = XI * YI * ZI;
    constexpr int NXC = So / TX, NYC = So / TY, NZC = So / TZ;
    constexpr int MTW = NMT / 2;
    static_assert(TX * TY * TZ == 32, "k2 tile must be 32 px");
    __shared__ __align__(16) f16 sm[NPX * PIX];

    int xc, yb, zb;
    tile_coords<NXC, NYC, NZC>(blockIdx.x, xc, yb, zb);
    const int x0 = xc * TX, y0 = yb * TY, z0 = zb * TZ;

    const int tid  = threadIdx.x;
    const int lane = tid & 63;
    const int wave = tid >> 6;
    const int i15  = lane & 15, quad = (lane >> 4) & 3;
    const int nt = wave & 1, mh = wave >> 1;
    const int p = nt * 16 + i15;
    const int lx = p % TX, ly = (p / TX) % TY, lz = p / (TX * TY);

    f32x4 acc[MTW];
#pragma unroll
    for (int m = 0; m < MTW; ++m) { f32x4 z = {0.f,0.f,0.f,0.f}; acc[m] = z; }

    for (int h = 0; h < CH; ++h) {
        __syncthreads();
        if (SRCF32) {
            const float* src = (const float*)in_;
            for (int it = tid; it < NPX * 8; it += 256) {
                const int xp = it % XI;
                const int rem = it / XI;
                const int row = rem % (YI * ZI);
                const int cc = rem / (YI * ZI);
                const int zr = row / YI, yr = row % YI;
                const size_t pos = (size_t)((z0 * 2 + zr) * Si2 + (y0 * 2 + yr) * Si + x0 * 2 + xp);
                const int cbase = h * 32 + (cc & 3) * 8;
                f16x8 v;
#pragma unroll
                for (int j = 0; j < 8; ++j) {
                    float x = src[(size_t)(cbase + j) * Si3 + pos] * src_scale;
                    f16 hi = (f16)x;
                    v[j] = (cc < 4) ? hi : (f16)(x - (float)hi);
                }
                const int slot = (xp >> 1) + (xp & 1) * TX;
                *(f16x8*)&sm[(row * XI + slot) * PIX + (cc & 3) * 8 + (cc >> 2) * 32] = v;
            }
        } else {
            const f16* src = (const f16*)in_;
            for (int it = tid; it < NPX * 8; it += 256) {
                const int cc = it & 7;
                const int pxl = it >> 3;
                const int xp = pxl % XI;
                const int row = pxl / XI;
                const int zr = row / YI, yr = row % YI;
                const size_t pos = (size_t)((z0 * 2 + zr) * Si2 + (y0 * 2 + yr) * Si + x0 * 2 + xp);
                f16x8 v = *(const f16x8*)&src[pos * (2 * SRC_C) + (cc >> 2) * SRC_C + h * 32 + (cc & 3) * 8];
                const int slot = (xp >> 1) + (xp & 1) * TX;
                *(f16x8*)&sm[(row * XI + slot) * PIX + (cc & 3) * 8 + (cc >> 2) * 32] = v;
            }
        }
        __syncthreads();

#pragma unroll
        for (int dz = 0; dz < 2; ++dz) {
#pragma unroll
            for (int dy = 0; dy < 2; ++dy) {
#pragma unroll
                for (int dx = 0; dx < 2; ++dx) {
                    const int tap = dz * 4 + dy * 2 + dx;
                    const int pix = ((2 * lz + dz) * YI + 2 * ly + dy) * XI + lx + dx * TX;
                    const f16x8 bh = *(const f16x8*)&sm[pix * PIX + quad * 8];
                    const f16x8 bl = *(const f16x8*)&sm[pix * PIX + 32 + quad * 8];
#pragma unroll
                    for (int m = 0; m < MTW; ++m) {
                        const int gm = mh * MTW + m;
                        const f16x8 awh = *(const f16x8*)&wp[((size_t)((tap * CH + h) * 2 + 0) * NMT + gm) * 512 + lane * 8];
                        const f16x8 awl = *(const f16x8*)&wp[((size_t)((tap * CH + h) * 2 + 1) * NMT + gm) * 512 + lane * 8];
                        acc[m] = __builtin_amdgcn_mfma_f32_16x16x32_f16(awh, bh, acc[m], 0, 0, 0);
                        acc[m] = __builtin_amdgcn_mfma_f32_16x16x32_f16(awh, bl, acc[m], 0, 0, 0);
                        acc[m] = __builtin_amdgcn_mfma_f32_16x16x32_f16(awl, bh, acc[m], 0, 0, 0);
                    }
                }
            }
        }
    }

    const int pg = (z0 + lz) * So2 + (y0 + ly) * So + x0 + lx;
#pragma unroll
    for (int m = 0; m < MTW; ++m) {
        const int gm = mh * MTW + m;
        if (GATE) {
            f16x4 chi = *(const f16x4*)&cx[(size_t)pg * 128 + gm * 16 + quad * 4];
            f16x4 clo = *(const f16x4*)&cx[(size_t)pg * 128 + 64 + gm * 16 + quad * 4];
            f16x4 nhi, nlo;
#pragma unroll
            for (int r = 0; r < 4; ++r) {
                const float g = 1.0f / (1.0f + expf(-fmaxf(acc[m][r], 0.f)));
                float v = ((float)chi[r] + (float)clo[r]) * g;
                f16 hi = (f16)v;
                nhi[r] = hi;
                nlo[r] = (f16)(v - (float)hi);
            }
            *(f16x4*)&cx[(size_t)pg * 128 + gm * 16 + quad * 4] = nhi;
            *(f16x4*)&cx[(size_t)pg * 128 + 64 + gm * 16 + quad * 4] = nlo;
        } else {
            f16x4 hi, lo;
#pragma unroll
            for (int r = 0; r < 4; ++r) {
                const float a = fmaxf(acc[m][r], 0.f);   // ConvBlock relu
                hi[r] = (f16)a;
                lo[r] = (f16)(a - (float)hi[r]);
            }
            *(f16x4*)&act_out[(size_t)pg * 128 + gm * 16 + quad * 4] = hi;
            *(f16x4*)&act_out[(size_t)pg * 128 + 64 + gm * 16 + quad * 4] = lo;
        }
    }
}

extern "C" void kernel_launch(void* const* d_in, const int* in_sizes, int n_in,
                              void* d_out, int out_size, void* d_ws, size_t ws_size,
                              hipStream_t stream)
{
    const float* x     = (const float*)d_in[0];
    const float* w_h   = (const float*)d_in[1];
    const float* w_c0  = (const float*)d_in[2];
    const float* w_r0  = (const float*)d_in[3];
    const float* w_r1  = (const float*)d_in[4];
    const float* w_c1  = (const float*)d_in[5];
    const float* w_out = (const float*)d_in[6];
    float* out = (float*)d_out;
    f16* ws = (f16*)d_ws;

    // ws layout (f16 units)
    size_t o = 0;
    f16* wp_h   = ws + o; o += (size_t)8 * 1 * 2 * 4 * 512;    // 64 entries
    f16* wp_c0  = ws + o; o += (size_t)8 * 2 * 2 * 4 * 512;    // 128
    f16* wp_r0  = ws + o; o += (size_t)27 * 2 * 2 * 4 * 512;   // 432
    f16* wp_r1  = ws + o; o += (size_t)27 * 2 * 2 * 4 * 512;   // 432
    f16* wp_c1  = ws + o; o += (size_t)27 * 2 * 2 * 4 * 512;   // 432
    f16* wp_out = ws + o; o += (size_t)27 * 2 * 2 * 2 * 512;   // 216
    const size_t ABUF = (size_t)32 * 32 * 32 * 128;            // C=64 act, 32^3
    f16* y_buf  = ws + o; o += ABUF;
    f16* t_buf  = ws + o; o += ABUF;
    f16* cx     = ws + o; o += ABUF;
    f16* hx_act = ws + o; o += (size_t)32 * 32 * 32 * 64;      // C=32 act, 32^3

    size_t offs[4];
    offs[0] = 0;
    offs[1] = offs[0] + (size_t)32 * 64 * 64 * 64;
    offs[2] = offs[1] + (size_t)32 * 32 * 32 * 32;
    offs[3] = offs[2] + (size_t)32 * 16 * 16 * 16;

    const dim3 blk(256);

    pack_all<<<dim3(1704), dim3(64), 0, stream>>>(
        w_h, w_c0, w_r0, w_r1, w_c1, w_out,
        wp_h, wp_c0, wp_r0, wp_r1, wp_c1, wp_out);

    // hx0 = 0.5 * conv_out(x) @64^3. Tile 16x4x2 (128 px), NT=4, MTW=1.
    conv_k3<64, 16, 4, 2, 4, 2, 32, true><<<dim3(2048), blk, 0, stream>>>(
        x, wp_out, nullptr, nullptr, out + offs[0], 0, 0.5f);

    // ---- level 0: 64 -> 32 ----
    conv_k2<32, 16, 2, 1, 4, 2, true, 64, false><<<dim3(1024), blk, 0, stream>>>(
        x, wp_c0, y_buf, nullptr, 1.0f);
    conv_k3<32, 16, 2, 2, 2, 4, 64, false><<<dim3(512), blk, 0, stream>>>(
        y_buf, wp_r0, nullptr, t_buf, nullptr, 1, 1.0f);
    conv_k3<32, 16, 2, 2, 2, 4, 64, false><<<dim3(512), blk, 0, stream>>>(
        t_buf, wp_r1, y_buf, y_buf, nullptr, 0, 1.0f);
    conv_k3<32, 16, 2, 2, 2, 4, 64, false><<<dim3(512), blk, 0, stream>>>(
        y_buf, wp_c1, nullptr, cx, nullptr, 0, 1.0f);
    conv_k2<32, 16, 2, 1, 4, 1, true, 32, true><<<dim3(1024), blk, 0, stream>>>(
        out + offs[0], wp_h, nullptr, cx, 2.0f);
    conv_k3<32, 16, 2, 2, 2, 2, 32, false><<<dim3(512), blk, 0, stream>>>(
        cx, wp_out, nullptr, hx_act, out + offs[1], 0, 0.5f);

    // ---- level 1: 32 -> 16 ----  (32-px tiles: grid 128)
    conv_k2<16, 16, 2, 1, 4, 2, false, 64, false><<<dim3(128), blk, 0, stream>>>(
        cx, wp_c0, y_buf, nullptr, 1.0f);
    conv_k3<16, 16, 2, 1, 1, 4, 64, false><<<dim3(128), blk, 0, stream>>>(
        y_buf, wp_r0, nullptr, t_buf, nullptr, 1, 1.0f);
    conv_k3<16, 16, 2, 1, 1, 4, 64, false><<<dim3(128), blk, 0, stream>>>(
        t_buf, wp_r1, y_buf, y_buf, nullptr, 0, 1.0f);
    conv_k3<16, 16, 2, 1, 1, 4, 64, false><<<dim3(128), blk, 0, stream>>>(
        y_buf, wp_c1, nullptr, cx, nullptr, 0, 1.0f);
    conv_k2<16, 16, 2, 1, 4, 1, false, 32, true><<<dim3(128), blk, 0, stream>>>(
        hx_act, wp_h, nullptr, cx, 1.0f);
    conv_k3<16, 16, 2, 1, 1, 2, 32, false><<<dim3(128), blk, 0, stream>>>(
        cx, wp_out, nullptr, hx_act, out + offs[2], 0, 0.5f);

    // ---- level 2: 16 -> 8 ----  (32-px tiles: grid 16)
    conv_k2<8, 8, 4, 1, 4, 2, false, 64, false><<<dim3(16), blk, 0, stream>>>(
        cx, wp_c0, y_buf, nullptr, 1.0f);
    conv_k3<8, 8, 4, 1, 1, 4, 64, false><<<dim3(16), blk, 0, stream>>>(
        y_buf, wp_r0, nullptr, t_buf, nullptr, 1, 1.0f);
    conv_k3<8, 8, 4, 1, 1, 4, 64, false><<<dim3(16), blk, 0, stream>>>(
        t_buf, wp_r1, y_buf, y_buf, nullptr, 0, 1.0f);
    conv_k3<8, 8, 4, 1, 1, 4, 64, false><<<dim3(16), blk, 0, stream>>>(
        y_buf, wp_c1, nullptr, cx, nullptr, 0, 1.0f);
    conv_k2<8, 8, 4, 1, 4, 1, false, 32, true><<<dim3(16), blk, 0, stream>>>(
        hx_act, wp_h, nullptr, cx, 1.0f);
    conv_k3<8, 8, 4, 1, 1, 2, 32, false><<<dim3(16), blk, 0, stream>>>(
        cx, wp_out, nullptr, nullptr, out + offs[3], 0, 0.5f);
}